// Round 5
// baseline (261.045 us; speedup 1.0000x reference)
//
#include <hip/hip_runtime.h>
#include <math.h>

typedef __attribute__((ext_vector_type(8))) short short8;
typedef __attribute__((ext_vector_type(4))) float float4v;

#define KDIM  512
#define NQKV  1536

__device__ __forceinline__ unsigned short f2bf(float f) {
    unsigned int u = __float_as_uint(f);
    u += 0x7FFFu + ((u >> 16) & 1u);   // round-to-nearest-even
    return (unsigned short)(u >> 16);
}
__device__ __forceinline__ float bf2f(unsigned short u) {
    return __uint_as_float(((unsigned int)u) << 16);
}

// async global->LDS DMA, 16 B per lane; LDS dest = wave-uniform base + lane*16
__device__ __forceinline__ void gl2lds16(const unsigned short* g, unsigned short* l) {
    __builtin_amdgcn_global_load_lds(
        (const __attribute__((address_space(1))) void*)g,
        (__attribute__((address_space(3))) void*)l, 16, 0, 0);
}

// ---------------- prep: cast x (roll -32 fused) + cast weights, one launch ----
__global__ __launch_bounds__(256) void prep_kernel(const float* __restrict__ x,
                                                   const float* __restrict__ wqkv,
                                                   const float* __restrict__ wproj,
                                                   unsigned short* __restrict__ xb,
                                                   unsigned short* __restrict__ wqkvb,
                                                   unsigned short* __restrict__ wprojb) {
    int bid = blockIdx.x;
    if (bid < 16384) {
        int tid = bid * 256 + threadIdx.x;
        int t = tid >> 7;               // token row 0..32767 (shifted order)
        int c = (tid & 127) << 2;
        int b = t >> 12, n = t & 4095;
        int src = (b << 12) | ((n + 32) & 4095);    // roll(x, -32)
        float4 v = *(const float4*)(x + (((size_t)src) << 9) + c);
        ushort4 o;
        o.x = f2bf(v.x); o.y = f2bf(v.y); o.z = f2bf(v.z); o.w = f2bf(v.w);
        *(ushort4*)(xb + (((size_t)t) << 9) + c) = o;
    } else {
        int tid = (bid - 16384) * 256 + threadIdx.x;
        int e = tid << 2;
        if (e < NQKV * KDIM) {
            float4 v = *(const float4*)(wqkv + e);
            ushort4 o; o.x = f2bf(v.x); o.y = f2bf(v.y); o.z = f2bf(v.z); o.w = f2bf(v.w);
            *(ushort4*)(wqkvb + e) = o;
        } else {
            int e2 = e - NQKV * KDIM;
            float4 v = *(const float4*)(wproj + e2);
            ushort4 o; o.x = f2bf(v.x); o.y = f2bf(v.y); o.z = f2bf(v.z); o.w = f2bf(v.w);
            *(ushort4*)(wprojb + e2) = o;
        }
    }
}

// ---------------- GEMM: C[M,N] = A[M,K] @ B[N,K]^T ----------------
// 128x128 tile, BK=32, 4 waves (2x2), DOUBLE-BUFFERED LDS with manual
// raw-s_barrier + per-wave s_waitcnt vmcnt(4) pipelining: tile i+1's DMAs stay
// in flight across the barrier (the __syncthreads vmcnt(0) drain was the stall).
// LDS row stride 32 (unpadded, DMA lane-contiguous); XOR swizzle on the GLOBAL
// address side: stored col-block p at row r holds source block p^((r>>1)&3),
// making fragment ds_read_b128 2-way per quarter-wave (free per m136).
template<int N, bool PROJ>
__global__ __launch_bounds__(256, 2) void gemm_kernel(
        const unsigned short* __restrict__ A,
        const unsigned short* __restrict__ B,
        unsigned short* __restrict__ Cb,
        float* __restrict__ Cf,
        const float* __restrict__ bias) {
    __shared__ __align__(16) unsigned short As[2][4096];   // 128 rows x 32 cols
    __shared__ __align__(16) unsigned short Bs[2][4096];
    const int bn = blockIdx.x, bm = blockIdx.y;
    const int tid = threadIdx.x;
    const int wave = tid >> 6, lane = tid & 63;
    const int quad = lane >> 4, l16 = lane & 15;
    const int wm = (wave >> 1) * 64, wn = (wave & 1) * 64;
    // DMA: chunk = 16 rows x 32 cols = 1 KB; 8 chunks; wave handles {wave, wave+4}.
    // Lane covers row chunk*16+(lane>>2), stored block lane&3 <- source block
    // (lane&3)^((srow>>1)&3)  (chunk*16 is 0 mod 8, so row>>1 & 3 == srow>>1 & 3).
    const int srow = lane >> 2;
    const int scol = ((lane & 3) ^ ((srow >> 1) & 3)) * 8;

    float4v acc[4][4] = {};

    const unsigned short* Abase = A + (size_t)(bm * 128) * KDIM;
    const unsigned short* Bbase = B + (size_t)(bn * 128) * KDIM;

    auto dma = [&](int k0, int buf) {
        #pragma unroll
        for (int j = 0; j < 2; j++) {
            int chunk = j * 4 + wave;               // 0..7
            int row = chunk * 16 + srow;            // 0..127
            gl2lds16(Abase + (size_t)row * KDIM + k0 + scol, &As[buf][chunk * 512]);
            gl2lds16(Bbase + (size_t)row * KDIM + k0 + scol, &Bs[buf][chunk * 512]);
        }
    };

    dma(0, 0);
    dma(32, 1);

    const int rblk = ((l16 >> 1) & 3);   // read-side swizzle term

    #pragma unroll
    for (int it = 0; it < 16; ++it) {
        if (it < 15) asm volatile("s_waitcnt vmcnt(4)" ::: "memory");
        else         asm volatile("s_waitcnt vmcnt(0)" ::: "memory");
        asm volatile("s_barrier" ::: "memory");
        const int buf = it & 1;
        short8 af[4], bf[4];
        #pragma unroll
        for (int mi = 0; mi < 4; mi++) {
            int r = wm + mi * 16 + l16;
            af[mi] = *(const short8*)(&As[buf][r * 32 + ((quad ^ rblk) * 8)]);
        }
        #pragma unroll
        for (int ni = 0; ni < 4; ni++) {
            int r = wn + ni * 16 + l16;
            bf[ni] = *(const short8*)(&Bs[buf][r * 32 + ((quad ^ rblk) * 8)]);
        }
        #pragma unroll
        for (int mi = 0; mi < 4; mi++)
            #pragma unroll
            for (int ni = 0; ni < 4; ni++)
                acc[mi][ni] = __builtin_amdgcn_mfma_f32_16x16x32_bf16(
                    af[mi], bf[ni], acc[mi][ni], 0, 0, 0);
        asm volatile("s_barrier" ::: "memory");   // all waves done reading buf
        if (it < 14) dma((it + 2) * 32, buf);
    }

    #pragma unroll
    for (int mi = 0; mi < 4; mi++) {
        #pragma unroll
        for (int r = 0; r < 4; r++) {
            int m = bm * 128 + wm + mi * 16 + quad * 4 + r;
            if (!PROJ) {
                #pragma unroll
                for (int ni = 0; ni < 4; ni++) {
                    int n = bn * 128 + wn + ni * 16 + l16;
                    Cb[(size_t)m * N + n] = f2bf(acc[mi][ni][r]);
                }
            } else {
                int b = m >> 12, p = m & 4095;
                int nrow = (p + 32) & 4095;      // roll(out, +32)
                float* orow = Cf + (((size_t)((b << 12) | nrow)) << 9);
                #pragma unroll
                for (int ni = 0; ni < 4; ni++) {
                    int n = bn * 128 + wn + ni * 16 + l16;
                    orow[n] = acc[mi][ni][r] + bias[n];
                }
            }
        }
    }
}

// ---------------- attention: 8x8 attention OVER HEADS per token ----------------
// einsum('bwhd,bwgd->bwhg'): per (window,position) token, S[h][g] = Q_h . K_g,
// softmax over g (scale 0.125), O[h] = sum_g P[h][g] V[g].
#define TPB_TOK 16
#define KV_STRIDE 1032   // 1024 + 8: token stride = 2064 B = 516 dw = 4 banks
__global__ __launch_bounds__(128) void attn_kernel(const unsigned short* __restrict__ qkvb,
                                                   unsigned short* __restrict__ aob) {
    __shared__ __align__(16) unsigned short smem[TPB_TOK * KV_STRIDE];
    const int tid = threadIdx.x;
    const int t0 = blockIdx.x * TPB_TOK;
    const int tok = tid >> 3, h = tid & 7;
    const int t = t0 + tok;

    // Q[h][0..63] global loads issue first (overlap with K/V staging)
    short8 qs[8];
    {
        const unsigned short* qsrc = qkvb + (size_t)t * NQKV + h * 64;
        #pragma unroll
        for (int dc = 0; dc < 8; dc++)
            qs[dc] = *(const short8*)(qsrc + dc * 8);
    }

    // stage K,V (rows of 1024 bf16 per token) into LDS, coalesced short8
    {
        int r = tid >> 3, cb = (tid & 7) * 8;
        const unsigned short* src = qkvb + (size_t)(t0 + r) * NQKV + 512;
        unsigned short* dst = smem + r * KV_STRIDE;
        #pragma unroll
        for (int p = 0; p < 16; p++) {
            int c = cb + p * 64;
            *(short8*)(dst + c) = *(const short8*)(src + c);
        }
    }
    __syncthreads();

    const unsigned short* row = smem + tok * KV_STRIDE;

    float qv[64];
    #pragma unroll
    for (int dc = 0; dc < 8; dc++)
        #pragma unroll
        for (int j = 0; j < 8; j++)
            qv[dc * 8 + j] = bf2f((unsigned short)qs[dc][j]);

    float s[8];
    #pragma unroll
    for (int g = 0; g < 8; g++) {
        float acc = 0.f;
        #pragma unroll
        for (int dc = 0; dc < 8; dc++) {
            short8 ks = *(const short8*)(row + g * 64 + dc * 8);
            #pragma unroll
            for (int j = 0; j < 8; j++)
                acc += qv[dc * 8 + j] * bf2f((unsigned short)ks[j]);
        }
        s[g] = acc;
    }

    float mx = s[0];
    #pragma unroll
    for (int g = 1; g < 8; g++) mx = fmaxf(mx, s[g]);
    float p[8], sum = 0.f;
    #pragma unroll
    for (int g = 0; g < 8; g++) { p[g] = __expf((s[g] - mx) * 0.125f); sum += p[g]; }
    float inv = 1.f / sum;
    #pragma unroll
    for (int g = 0; g < 8; g++) p[g] *= inv;

    float o[64];
    #pragma unroll
    for (int j = 0; j < 64; j++) o[j] = 0.f;
    #pragma unroll
    for (int g = 0; g < 8; g++) {
        #pragma unroll
        for (int dc = 0; dc < 8; dc++) {
            short8 vs = *(const short8*)(row + 512 + g * 64 + dc * 8);
            #pragma unroll
            for (int j = 0; j < 8; j++)
                o[dc * 8 + j] += p[g] * bf2f((unsigned short)vs[j]);
        }
    }

    // scrambled write replicating transpose(0,2,1,3).reshape:
    // proj-in row = win*64 + h*8 + w/8 ; col = (w%8)*64 + d
    int win = t >> 6, w = t & 63;
    unsigned short* dst = aob + (size_t)(win * 64 + h * 8 + (w >> 3)) * 512 + (w & 7) * 64;
    #pragma unroll
    for (int dc = 0; dc < 16; dc++) {
        ushort4 ov;
        ov.x = f2bf(o[dc * 4 + 0]); ov.y = f2bf(o[dc * 4 + 1]);
        ov.z = f2bf(o[dc * 4 + 2]); ov.w = f2bf(o[dc * 4 + 3]);
        *(ushort4*)(dst + dc * 4) = ov;
    }
}

extern "C" void kernel_launch(void* const* d_in, const int* in_sizes, int n_in,
                              void* d_out, int out_size, void* d_ws, size_t ws_size,
                              hipStream_t stream) {
    const float* x      = (const float*)d_in[0];
    const float* w_qkv  = (const float*)d_in[1];
    const float* w_proj = (const float*)d_in[2];
    const float* b_proj = (const float*)d_in[3];
    float* out = (float*)d_out;

    char* ws = (char*)d_ws;
    unsigned short* xb     = (unsigned short*)(ws);                 // 32 MB
    unsigned short* wqkvb  = (unsigned short*)(ws + 33554432);      // 1.5 MB
    unsigned short* wprojb = (unsigned short*)(ws + 35127296);      // 0.5 MB
    unsigned short* qkvb   = (unsigned short*)(ws + 35651584);      // 96 MB
    unsigned short* aob    = (unsigned short*)(ws + 136314880);     // 32 MB

    prep_kernel<<<16384 + 1024, 256, 0, stream>>>(x, w_qkv, w_proj, xb, wqkvb, wprojb);
    gemm_kernel<NQKV, false><<<dim3(12, 256), 256, 0, stream>>>(xb, wqkvb, qkvb, nullptr, nullptr);
    attn_kernel<<<2048, 128, 0, stream>>>(qkvb, aob);
    gemm_kernel<512, true><<<dim3(4, 256), 256, 0, stream>>>(aob, wprojb, nullptr, out, b_proj);
}